// Round 4
// baseline (232.937 us; speedup 1.0000x reference)
//
#include <hip/hip_runtime.h>
#include <hip/hip_bf16.h>

typedef __attribute__((ext_vector_type(8))) short short8;
typedef __attribute__((ext_vector_type(4))) float f32x4;
typedef unsigned short u16;
typedef __attribute__((ext_vector_type(4))) u16 u16x4;
typedef __attribute__((ext_vector_type(8))) u16 u16x8;

#define LN_EPS 1e-5f
#define NT 384
#define SD 64
#define CH 32
#define CO 128

#define MFMA16(a, b, c) __builtin_amdgcn_mfma_f32_16x16x32_bf16(a, b, c, 0, 0, 0)

static __device__ __forceinline__ u16 f2bf(float v) {
    __hip_bfloat16 h = __float2bfloat16(v);
    return *reinterpret_cast<u16*>(&h);
}

// ---------------- Kernel 1: LayerNorm + dual projection + mask ----------------
__global__ __launch_bounds__(256) void ln_proj_kernel(
    const float* __restrict__ m, const int* __restrict__ mask,
    const float* __restrict__ gamma, const float* __restrict__ beta,
    const float* __restrict__ Wa, const float* __restrict__ Wb,
    u16* __restrict__ a_out, u16* __restrict__ b_out)
{
    __shared__ float Wl[2][64][33];
    __shared__ float mn_s[64][65];
    __shared__ float mf_s[64];
    int n = blockIdx.x, tid = threadIdx.x;
    int wv = tid >> 6, lane = tid & 63;

    #pragma unroll
    for (int rep = 0; rep < 2; ++rep) {
        int p = rep * 1024 + tid * 4;
        int c = p >> 6, k0 = p & 63;
        float4 va = *(const float4*)(Wa + p);
        float4 vb = *(const float4*)(Wb + p);
        Wl[0][k0 + 0][c] = va.x; Wl[0][k0 + 1][c] = va.y;
        Wl[0][k0 + 2][c] = va.z; Wl[0][k0 + 3][c] = va.w;
        Wl[1][k0 + 0][c] = vb.x; Wl[1][k0 + 1][c] = vb.y;
        Wl[1][k0 + 2][c] = vb.z; Wl[1][k0 + 3][c] = vb.w;
    }

    float gl = gamma[lane], bl = beta[lane];
    for (int it = 0; it < 16; ++it) {
        int s = wv * 16 + it;
        float x = m[(s * NT + n) * 64 + lane];
        float v = x;
        #pragma unroll
        for (int off = 1; off < 64; off <<= 1) v += __shfl_xor(v, off);
        float mu = v * (1.0f / 64.0f);
        float d = x - mu;
        float v2 = d * d;
        #pragma unroll
        for (int off = 1; off < 64; off <<= 1) v2 += __shfl_xor(v2, off);
        float rstd = rsqrtf(v2 * (1.0f / 64.0f) + LN_EPS);
        mn_s[lane][s] = d * rstd * gl + bl;
    }
    if (tid < 64) mf_s[tid] = (float)mask[tid * NT + n];
    __syncthreads();

    int c = tid & 31, sg = tid >> 5;
    float accA[8], accB[8];
    #pragma unroll
    for (int j = 0; j < 8; ++j) { accA[j] = 0.f; accB[j] = 0.f; }
    for (int k = 0; k < 64; ++k) {
        float wa = Wl[0][k][c], wb = Wl[1][k][c];
        #pragma unroll
        for (int j = 0; j < 8; ++j) {
            float mnv = mn_s[k][sg * 8 + j];
            accA[j] += mnv * wa;
            accB[j] += mnv * wb;
        }
    }
    u16x8 pa, pb;
    #pragma unroll
    for (int j = 0; j < 8; ++j) {
        float mfv = mf_s[sg * 8 + j];
        pa[j] = f2bf(accA[j] * mfv);
        pb[j] = f2bf(accB[j] * mfv);
    }
    int off = n * (CH * SD) + c * SD + sg * 8;
    *(u16x8*)(a_out + off) = pa;
    *(u16x8*)(b_out + off) = pb;
}

// ---------------- Kernel 2: denom + Wo->bf16 merged (one launch) ----------------
__global__ __launch_bounds__(384) void prep_kernel(const int* __restrict__ mask,
                                                   float* __restrict__ rdenom,
                                                   const float* __restrict__ wo,
                                                   u16* __restrict__ wo_bf)
{
    int bid = blockIdx.x, tid = threadIdx.x;
    if (bid < NT) {
        int i = bid, j = tid;
        int acc = 0;
        #pragma unroll 8
        for (int s = 0; s < SD; ++s)
            acc += mask[s * NT + i] * mask[s * NT + j];
        rdenom[i * NT + j] = 1.0f / (float)max(acc, 1);
    } else {
        int idx = (bid - NT) * 384 + tid;
        if (idx < CO * 1024) wo_bf[idx] = f2bf(wo[idx]);
    }
}

// ---------------- Kernel 3: fused OPM + down-projection, barrier-free ----------------
// Block = 4 waves, tile 16 i x 8 j. Wave (jh=w&1, nh=w>>1) owns j-set {jh*4..+3}
// and o-set {nh*64..+63}. Per c-chunk (32 total):
//   stage A (16 MFMA): zc[j',d,i] for its own 4 j  -> wave-PRIVATE LDS buf (4 KB, dbuf)
//   stage B (16 MFMA): acc[j',i][o] += zc @ wo-chunk (persistent acc)
// No __syncthreads anywhere. Registers rotate via 2-phase unroll (no copies):
// prefetch distance = 2 chunks for both wo and a fragments.
// LDS granule layout: g(j',dq,i) = (j'*4+dq)*16 + (i ^ (dq<<1)) -> b64 writes
// 2 lanes/bank (free), b128 reads perfectly balanced.
__global__ __launch_bounds__(256, 2) void opm_kernel(
    const u16* __restrict__ a2,   // [384][32][64]  a[i][c][s]
    const u16* __restrict__ bt,   // [384][32][64]  b[j][d][s]
    const u16* __restrict__ wo,   // [128][1024]
    const float* __restrict__ rdenom,
    const float* __restrict__ bo,
    float* __restrict__ out)      // [384][384][128]
{
    __shared__ u16 zlds[4][2][2048];   // 4 waves x 2 bufs x 4 KB

    int bid = blockIdx.x;
    int ig = bid / 48;
    int jb = bid % 48;
    int tid = threadIdx.x;
    int w = tid >> 6, lane = tid & 63;
    int l15 = lane & 15, quad = lane >> 4;
    int jh = w & 1, nh = w >> 1;

    // persistent bt fragments: 8 mtiles (4 j x 2 d-half), rows [d][s]
    short8 btf[8][2];
    #pragma unroll
    for (int mt = 0; mt < 8; ++mt) {
        int jq = mt >> 1, dh = mt & 1;
        const u16* p = bt + ((jb * 8 + jh * 4 + jq) * CH + dh * 16 + l15) * SD + quad * 8;
        btf[mt][0] = *(const short8*)(p);
        btf[mt][1] = *(const short8*)(p + 32);
    }

    const u16* abase = a2 + (ig * 16 + l15) * (CH * SD) + quad * 8;
    const u16* wbase = wo + (nh * 64 + l15) * 1024 + quad * 8;
    u16* zb0 = &zlds[w][0][0];
    u16* zb1 = &zlds[w][1][0];

    f32x4 acc[4][4];
    #pragma unroll
    for (int mi = 0; mi < 4; ++mi)
        #pragma unroll
        for (int ni = 0; ni < 4; ++ni)
            acc[mi][ni] = (f32x4){0.f, 0.f, 0.f, 0.f};

    auto loadAf = [&](int c, short8* dst) {
        dst[0] = *(const short8*)(abase + c * 64);
        dst[1] = *(const short8*)(abase + c * 64 + 32);
    };
    auto loadWof = [&](int c, short8* dst) {
        #pragma unroll
        for (int ni = 0; ni < 4; ++ni)
            dst[ni] = *(const short8*)(wbase + ni * 16 * 1024 + c * 32);
    };
    auto stageA = [&](const short8* a, u16* buf) {
        #pragma unroll
        for (int mt = 0; mt < 8; ++mt) {
            f32x4 za = {0.f, 0.f, 0.f, 0.f};
            za = MFMA16(btf[mt][0], a[0], za);
            za = MFMA16(btf[mt][1], a[1], za);
            int jq = mt >> 1, dh = mt & 1;
            int dq = dh * 2 + (quad >> 1);
            int gran = (jq * 4 + dq) * 16 + (l15 ^ (dq << 1));
            u16x4 pk;
            #pragma unroll
            for (int r = 0; r < 4; ++r) pk[r] = f2bf(za[r]);
            *(u16x4*)((char*)buf + gran * 16 + (quad & 1) * 8) = pk;
        }
    };
    auto stageB = [&](const u16* buf, const short8* wof) {
        short8 zf[4];
        #pragma unroll
        for (int mi = 0; mi < 4; ++mi) {
            int gran = (mi * 4 + quad) * 16 + (l15 ^ (quad << 1));
            zf[mi] = *(const short8*)((const char*)buf + gran * 16);
        }
        #pragma unroll
        for (int mi = 0; mi < 4; ++mi)
            #pragma unroll
            for (int ni = 0; ni < 4; ++ni)
                acc[mi][ni] = MFMA16(zf[mi], wof[ni], acc[mi][ni]);
    };

    // ---- pipeline prologue ----
    short8 af[2][2], afT[2], wof[2][4];
    loadAf(0, afT);
    loadWof(0, wof[0]);
    loadWof(1, wof[1]);
    loadAf(1, af[1]);     // chunk 1
    loadAf(2, af[0]);     // chunk 2
    stageA(afT, zb0);     // chunk 0 -> buf0

    // ---- main loop: 2 chunks per iteration, no barriers ----
    for (int t = 0; t < 32; t += 2) {
        // phase 0: consume chunk t, produce chunk t+1
        stageB(zb0, wof[0]);
        loadWof(t + 2 < 32 ? t + 2 : 31, wof[0]);
        stageA(af[1], zb1);
        loadAf(t + 3 < 32 ? t + 3 : 31, af[1]);
        // phase 1: consume chunk t+1, produce chunk t+2
        stageB(zb1, wof[1]);
        loadWof(t + 3 < 32 ? t + 3 : 31, wof[1]);
        if (t + 2 < 32) stageA(af[0], zb0);
        loadAf(t + 4 < 32 ? t + 4 : 31, af[0]);
    }

    // ---- epilogue: rdenom, bias, store ----
    float bov[4];
    #pragma unroll
    for (int ni = 0; ni < 4; ++ni) bov[ni] = bo[nh * 64 + ni * 16 + l15];
    #pragma unroll
    for (int mi = 0; mi < 4; ++mi) {
        int j_g = jb * 8 + jh * 4 + mi;
        #pragma unroll
        for (int r = 0; r < 4; ++r) {
            int i_g = ig * 16 + quad * 4 + r;
            float rd = rdenom[i_g * NT + j_g];
            float* orow = out + (i_g * NT + j_g) * CO + nh * 64 + l15;
            #pragma unroll
            for (int ni = 0; ni < 4; ++ni)
                orow[ni * 16] = acc[mi][ni][r] * rd + bov[ni];
        }
    }
}

// ---------------- launch ----------------
extern "C" void kernel_launch(void* const* d_in, const int* in_sizes, int n_in,
                              void* d_out, int out_size, void* d_ws, size_t ws_size,
                              hipStream_t stream) {
    const float* m     = (const float*)d_in[0];
    const int*   mask  = (const int*)d_in[1];
    const float* gamma = (const float*)d_in[2];
    const float* beta  = (const float*)d_in[3];
    const float* Wa    = (const float*)d_in[4];
    const float* Wb    = (const float*)d_in[5];
    const float* Wo    = (const float*)d_in[6];
    const float* bo    = (const float*)d_in[7];
    float* out = (float*)d_out;

    char* ws = (char*)d_ws;
    u16*   a2    = (u16*)(ws);
    u16*   btp   = (u16*)(ws + 1572864);
    u16*   wo_bf = (u16*)(ws + 3145728);
    float* rden  = (float*)(ws + 3407872);

    ln_proj_kernel<<<NT, 256, 0, stream>>>(m, mask, gamma, beta, Wa, Wb, a2, btp);
    prep_kernel<<<NT + (CO * 1024 + 383) / 384, 384, 0, stream>>>(mask, rden, Wo, wo_bf);
    opm_kernel<<<24 * 48, 256, 0, stream>>>(a2, btp, wo_bf, rden, bo, out);
}

// Round 5
// 225.898 us; speedup vs baseline: 1.0312x; 1.0312x over previous
//
#include <hip/hip_runtime.h>
#include <hip/hip_bf16.h>

typedef __attribute__((ext_vector_type(8))) short short8;
typedef __attribute__((ext_vector_type(4))) float f32x4;
typedef unsigned short u16;
typedef __attribute__((ext_vector_type(4))) u16 u16x4;
typedef __attribute__((ext_vector_type(8))) u16 u16x8;

#define LN_EPS 1e-5f
#define NT 384
#define SD 64
#define CH 32
#define CO 128

#define MFMA16(a, b, c) __builtin_amdgcn_mfma_f32_16x16x32_bf16(a, b, c, 0, 0, 0)
// LDS-only barrier: drains lgkm (LDS) but NOT vmcnt -> global prefetches stay in flight.
#define LDS_BARRIER() asm volatile("s_waitcnt lgkmcnt(0)\n\ts_barrier" ::: "memory")

static __device__ __forceinline__ u16 f2bf(float v) {
    __hip_bfloat16 h = __float2bfloat16(v);
    return *reinterpret_cast<u16*>(&h);
}

// ---------------- Kernel 1: LayerNorm + dual projection + mask ----------------
// Block = 128 thr, one (n, 16-s window) per block -> grid 1536 (4x R4 parallelism).
__global__ __launch_bounds__(128) void ln_proj_kernel(
    const float* __restrict__ m, const int* __restrict__ mask,
    const float* __restrict__ gamma, const float* __restrict__ beta,
    const float* __restrict__ Wa, const float* __restrict__ Wb,
    u16* __restrict__ a_out, u16* __restrict__ b_out)
{
    __shared__ float Wl[2][64][33];   // [which][k][c], bank = (k+c)%32 conflict-free reads
    __shared__ float mn_s[64][20];    // [k][s-window], stride 20 -> 16B-aligned f32x4 reads
    __shared__ float mf_s[16];
    int bid = blockIdx.x;
    int n = bid >> 2, s0 = (bid & 3) * 16;
    int tid = threadIdx.x;
    int wv = tid >> 6, lane = tid & 63;

    #pragma unroll
    for (int rep = 0; rep < 4; ++rep) {
        int p = rep * 512 + tid * 4;
        int c = p >> 6, k0 = p & 63;
        float4 va = *(const float4*)(Wa + p);
        float4 vb = *(const float4*)(Wb + p);
        Wl[0][k0 + 0][c] = va.x; Wl[0][k0 + 1][c] = va.y;
        Wl[0][k0 + 2][c] = va.z; Wl[0][k0 + 3][c] = va.w;
        Wl[1][k0 + 0][c] = vb.x; Wl[1][k0 + 1][c] = vb.y;
        Wl[1][k0 + 2][c] = vb.z; Wl[1][k0 + 3][c] = vb.w;
    }

    float gl = gamma[lane], bl = beta[lane];
    #pragma unroll 2
    for (int it = 0; it < 8; ++it) {
        int sw = wv * 8 + it;
        int s = s0 + sw;
        float x = m[(s * NT + n) * 64 + lane];
        float v = x;
        #pragma unroll
        for (int off = 1; off < 64; off <<= 1) v += __shfl_xor(v, off);
        float mu = v * (1.0f / 64.0f);
        float d = x - mu;
        float v2 = d * d;
        #pragma unroll
        for (int off = 1; off < 64; off <<= 1) v2 += __shfl_xor(v2, off);
        float rstd = rsqrtf(v2 * (1.0f / 64.0f) + LN_EPS);
        mn_s[lane][sw] = d * rstd * gl + bl;
    }
    if (tid < 16) mf_s[tid] = (float)mask[(s0 + tid) * NT + n];
    __syncthreads();

    // projection: thread (c, which, sg) -> 8 s values, f32x4 broadcast reads of mn
    int c = tid & 31, which = (tid >> 5) & 1, sg = tid >> 6;
    float acc[8];
    #pragma unroll
    for (int j = 0; j < 8; ++j) acc[j] = 0.f;
    for (int k = 0; k < 64; ++k) {
        float wk = Wl[which][k][c];
        f32x4 m0 = *(const f32x4*)&mn_s[k][sg * 8];
        f32x4 m1 = *(const f32x4*)&mn_s[k][sg * 8 + 4];
        #pragma unroll
        for (int j = 0; j < 4; ++j) {
            acc[j]     += m0[j] * wk;
            acc[4 + j] += m1[j] * wk;
        }
    }
    u16x8 pk;
    #pragma unroll
    for (int j = 0; j < 8; ++j) pk[j] = f2bf(acc[j] * mf_s[sg * 8 + j]);
    u16* dst = which ? b_out : a_out;
    *(u16x8*)(dst + n * (CH * SD) + c * SD + s0 + sg * 8) = pk;
}

// ---------------- Kernel 2: denom + Wo->bf16 merged ----------------
__global__ __launch_bounds__(384) void prep_kernel(const int* __restrict__ mask,
                                                   float* __restrict__ rdenom,
                                                   const float* __restrict__ wo,
                                                   u16* __restrict__ wo_bf)
{
    int bid = blockIdx.x, tid = threadIdx.x;
    if (bid < NT) {
        int i = bid, j = tid;
        int acc = 0;
        #pragma unroll 8
        for (int s = 0; s < SD; ++s)
            acc += mask[s * NT + i] * mask[s * NT + j];
        rdenom[i * NT + j] = 1.0f / (float)max(acc, 1);
    } else {
        int idx = (bid - NT) * 384 + tid;
        if (idx < CO * 1024) wo_bf[idx] = f2bf(wo[idx]);
    }
}

// ---------------- Kernel 3: fused OPM + down-projection ----------------
// R3 partition (shared z, no stage-A duplication) + true 2-phase register
// rotation (no copies) + LDS-only barrier (1 per chunk, vm prefetches live).
// Block = 4 waves, tile 16 i x 8 j x 128 o. Per c-chunk:
//   stage A (8 MFMA/wave):  z[j*16+i][d0..31] -> dbuf LDS (8 KB)
//   stage B (16 MFMA/wave): acc[(j,i)][o] += z-chunk @ wo-chunk
__global__ __launch_bounds__(256, 2) void opm_kernel(
    const u16* __restrict__ a2,   // [384][32][64]  a[i][c][s]
    const u16* __restrict__ bt,   // [384][32][64]  b[j][d][s]
    const u16* __restrict__ wo,   // [128][1024]
    const float* __restrict__ rdenom,
    const float* __restrict__ bo,
    float* __restrict__ out)      // [384][384][128]
{
    __shared__ u16 zbuf[2][128 * 32];   // 2 x 8 KB

    int bid = blockIdx.x;
    int ig = bid / 48;
    int jb = bid % 48;
    int tid = threadIdx.x;
    int w = tid >> 6, lane = tid & 63;
    int l15 = lane & 15, quad = lane >> 4;
    int mh = w & 1, nh = w >> 1;
    int swz = (l15 >> 1) & 3;

    // persistent bt fragments: wave w owns stage-A mtiles w*4..w*4+3 (j=mt>>1, dh=mt&1)
    short8 btf[4][2];
    #pragma unroll
    for (int mt4 = 0; mt4 < 4; ++mt4) {
        int mt = w * 4 + mt4;
        int j = mt >> 1, dh = mt & 1;
        const u16* p = bt + ((jb * 8 + j) * CH + dh * 16 + l15) * SD + quad * 8;
        btf[mt4][0] = *(const short8*)(p);
        btf[mt4][1] = *(const short8*)(p + 32);
    }

    const u16* abase = a2 + (ig * 16 + l15) * (CH * SD) + quad * 8;
    const u16* wbase = wo + (nh * 64 + l15) * 1024 + quad * 8;

    f32x4 acc[4][4];
    #pragma unroll
    for (int mi = 0; mi < 4; ++mi)
        #pragma unroll
        for (int ni = 0; ni < 4; ++ni)
            acc[mi][ni] = (f32x4){0.f, 0.f, 0.f, 0.f};

    auto loadAf = [&](int c, short8* dst) {
        dst[0] = *(const short8*)(abase + c * 64);
        dst[1] = *(const short8*)(abase + c * 64 + 32);
    };
    auto loadWof = [&](int c, short8* dst) {
        #pragma unroll
        for (int ni = 0; ni < 4; ++ni)
            dst[ni] = *(const short8*)(wbase + ni * 16 * 1024 + c * 32);
    };
    auto stageA = [&](const short8* a, u16* buf) {
        #pragma unroll
        for (int mt4 = 0; mt4 < 4; ++mt4) {
            f32x4 za = {0.f, 0.f, 0.f, 0.f};
            za = MFMA16(btf[mt4][0], a[0], za);
            za = MFMA16(btf[mt4][1], a[1], za);
            int mt = w * 4 + mt4;
            int j = mt >> 1;
            int row = j * 16 + l15;                       // (j, i=l15)
            int chunk = ((mt & 1) * 2 + (quad >> 1)) ^ swz;
            u16x4 pk;
            #pragma unroll
            for (int r = 0; r < 4; ++r) pk[r] = f2bf(za[r]);
            *(u16x4*)((char*)buf + row * 64 + chunk * 16 + (quad & 1) * 8) = pk;
        }
    };
    auto stageB = [&](const u16* buf, const short8* wof) {
        short8 zf[4];
        int chunk = quad ^ swz;
        #pragma unroll
        for (int mi = 0; mi < 4; ++mi) {
            int row = (mh * 4 + mi) * 16 + l15;           // (j=mh*4+mi, i=l15)
            zf[mi] = *(const short8*)((const char*)buf + row * 64 + chunk * 16);
        }
        #pragma unroll
        for (int mi = 0; mi < 4; ++mi)
            #pragma unroll
            for (int ni = 0; ni < 4; ++ni)
                acc[mi][ni] = MFMA16(zf[mi], wof[ni], acc[mi][ni]);
    };

    // ---- pipeline prologue ----
    short8 afA[2], afB[2], wofA[4], wofB[4];
    loadAf(0, afA);
    loadAf(1, afB);
    loadWof(0, wofA);
    loadWof(1, wofB);
    stageA(afA, zbuf[0]);      // chunk 0 -> buf0 (waits only on afA)
    loadAf(2, afA);            // refill: chunk 2
    LDS_BARRIER();

    // ---- main loop: 2 chunks/iter, 1 LDS barrier per chunk, no reg copies ----
    for (int t = 0; t < 32; t += 2) {
        // phase 0: consume chunk t (buf0,wofA), produce t+1 (buf1,afB)
        stageB(zbuf[0], wofA);
        stageA(afB, zbuf[1]);
        loadWof(t + 2 < 32 ? t + 2 : 31, wofA);
        loadAf(t + 3 < 32 ? t + 3 : 31, afB);
        LDS_BARRIER();
        // phase 1: consume chunk t+1 (buf1,wofB), produce t+2 (buf0,afA)
        stageB(zbuf[1], wofB);
        if (t + 2 < 32) stageA(afA, zbuf[0]);
        loadWof(t + 3 < 32 ? t + 3 : 31, wofB);
        loadAf(t + 4 < 32 ? t + 4 : 31, afA);
        LDS_BARRIER();
    }

    // ---- epilogue: rdenom, bias, store ----
    float bov[4];
    #pragma unroll
    for (int ni = 0; ni < 4; ++ni) bov[ni] = bo[nh * 64 + ni * 16 + l15];
    #pragma unroll
    for (int mi = 0; mi < 4; ++mi) {
        int j_g = jb * 8 + mh * 4 + mi;
        #pragma unroll
        for (int r = 0; r < 4; ++r) {
            int i_g = ig * 16 + quad * 4 + r;
            float rd = rdenom[i_g * NT + j_g];
            float* orow = out + (i_g * NT + j_g) * CO + nh * 64 + l15;
            #pragma unroll
            for (int ni = 0; ni < 4; ++ni)
                orow[ni * 16] = acc[mi][ni][r] * rd + bov[ni];
        }
    }
}

// ---------------- launch ----------------
extern "C" void kernel_launch(void* const* d_in, const int* in_sizes, int n_in,
                              void* d_out, int out_size, void* d_ws, size_t ws_size,
                              hipStream_t stream) {
    const float* m     = (const float*)d_in[0];
    const int*   mask  = (const int*)d_in[1];
    const float* gamma = (const float*)d_in[2];
    const float* beta  = (const float*)d_in[3];
    const float* Wa    = (const float*)d_in[4];
    const float* Wb    = (const float*)d_in[5];
    const float* Wo    = (const float*)d_in[6];
    const float* bo    = (const float*)d_in[7];
    float* out = (float*)d_out;

    char* ws = (char*)d_ws;
    u16*   a2    = (u16*)(ws);
    u16*   btp   = (u16*)(ws + 1572864);
    u16*   wo_bf = (u16*)(ws + 3145728);
    float* rden  = (float*)(ws + 3407872);

    ln_proj_kernel<<<NT * 4, 128, 0, stream>>>(m, mask, gamma, beta, Wa, Wb, a2, btp);
    prep_kernel<<<NT + (CO * 1024 + 383) / 384, 384, 0, stream>>>(mask, rden, Wo, wo_bf);
    opm_kernel<<<24 * 48, 256, 0, stream>>>(a2, btp, wo_bf, rden, bo, out);
}

// Round 6
// 191.649 us; speedup vs baseline: 1.2154x; 1.1787x over previous
//
#include <hip/hip_runtime.h>
#include <hip/hip_bf16.h>

typedef __attribute__((ext_vector_type(8))) short short8;
typedef __attribute__((ext_vector_type(4))) float f32x4;
typedef unsigned short u16;
typedef __attribute__((ext_vector_type(4))) u16 u16x4;
typedef __attribute__((ext_vector_type(8))) u16 u16x8;

#define LN_EPS 1e-5f
#define NT 384
#define SD 64
#define CH 32
#define CO 128

#define MFMA16(a, b, c) __builtin_amdgcn_mfma_f32_16x16x32_bf16(a, b, c, 0, 0, 0)
// LDS-only barrier: drains lgkm but NOT vmcnt -> global prefetches stay in flight.
#define LDS_BARRIER() asm volatile("s_waitcnt lgkmcnt(0)\n\ts_barrier" ::: "memory")

static __device__ __forceinline__ u16 f2bf(float v) {
    __hip_bfloat16 h = __float2bfloat16(v);
    return *reinterpret_cast<u16*>(&h);
}

// ---------------- Kernel 1: LayerNorm + dual projection + mask ----------------
// Block = 128 thr, one (n, 16-s window). a-side written DIRECTLY in per-chunk
// MFMA fragment order: aws[((c*24+ig)*2+h)*512 + (quad*16+l15)*8 + j]
// (l15 = i%16, quad = s-oct within 32-half, h = s>>5) -> opm loadAf is one
// contiguous 1 KB segment per instruction.
__global__ __launch_bounds__(128) void ln_proj_kernel(
    const float* __restrict__ m, const int* __restrict__ mask,
    const float* __restrict__ gamma, const float* __restrict__ beta,
    const float* __restrict__ Wa, const float* __restrict__ Wb,
    u16* __restrict__ aws, u16* __restrict__ b_out)
{
    __shared__ float Wl[2][64][33];   // [which][k][c], bank=(k+c)%32 conflict-free
    __shared__ float mn_s[64][20];    // [k][s-window]
    __shared__ float mf_s[16];
    int bid = blockIdx.x;
    int n = bid >> 2, s0 = (bid & 3) * 16;
    int tid = threadIdx.x;
    int wv = tid >> 6, lane = tid & 63;

    #pragma unroll
    for (int rep = 0; rep < 4; ++rep) {
        int p = rep * 512 + tid * 4;
        int c = p >> 6, k0 = p & 63;
        float4 va = *(const float4*)(Wa + p);
        float4 vb = *(const float4*)(Wb + p);
        Wl[0][k0 + 0][c] = va.x; Wl[0][k0 + 1][c] = va.y;
        Wl[0][k0 + 2][c] = va.z; Wl[0][k0 + 3][c] = va.w;
        Wl[1][k0 + 0][c] = vb.x; Wl[1][k0 + 1][c] = vb.y;
        Wl[1][k0 + 2][c] = vb.z; Wl[1][k0 + 3][c] = vb.w;
    }

    float gl = gamma[lane], bl = beta[lane];
    #pragma unroll 2
    for (int it = 0; it < 8; ++it) {
        int sw = wv * 8 + it;
        int s = s0 + sw;
        float x = m[(s * NT + n) * 64 + lane];
        float v = x;
        #pragma unroll
        for (int off = 1; off < 64; off <<= 1) v += __shfl_xor(v, off);
        float mu = v * (1.0f / 64.0f);
        float d = x - mu;
        float v2 = d * d;
        #pragma unroll
        for (int off = 1; off < 64; off <<= 1) v2 += __shfl_xor(v2, off);
        float rstd = rsqrtf(v2 * (1.0f / 64.0f) + LN_EPS);
        mn_s[lane][sw] = d * rstd * gl + bl;
    }
    if (tid < 16) mf_s[tid] = (float)mask[(s0 + tid) * NT + n];
    __syncthreads();

    int c = tid & 31, which = (tid >> 5) & 1, sg = tid >> 6;
    float acc[8];
    #pragma unroll
    for (int j = 0; j < 8; ++j) acc[j] = 0.f;
    for (int k = 0; k < 64; ++k) {
        float wk = Wl[which][k][c];
        f32x4 m0 = *(const f32x4*)&mn_s[k][sg * 8];
        f32x4 m1 = *(const f32x4*)&mn_s[k][sg * 8 + 4];
        #pragma unroll
        for (int j = 0; j < 4; ++j) {
            acc[j]     += m0[j] * wk;
            acc[4 + j] += m1[j] * wk;
        }
    }
    u16x8 pk;
    #pragma unroll
    for (int j = 0; j < 8; ++j) pk[j] = f2bf(acc[j] * mf_s[sg * 8 + j]);
    if (which) {
        // b: natural [n][d][s] layout (loaded once per opm block)
        *(u16x8*)(b_out + n * (CH * SD) + c * SD + s0 + sg * 8) = pk;
    } else {
        // a: fragment order
        int h = (s0 + sg * 8) >> 5;
        int quadIdx = ((s0 >> 3) + sg) & 3;
        int ig = n >> 4, l15 = n & 15;
        *(u16x8*)(aws + ((c * 24 + ig) * 2 + h) * 512 + (quadIdx * 16 + l15) * 8) = pk;
    }
}

// ---------------- Kernel 2: denom + Wo -> per-chunk fragment order ----------------
// wos[((c*8+g)*64 + lane)*8 + j] = wo[(g*16 + (lane&15)) * 1024 + c*32 + (lane>>4)*8 + j]
__global__ __launch_bounds__(384) void prep_kernel(const int* __restrict__ mask,
                                                   float* __restrict__ rdenom,
                                                   const float* __restrict__ wo,
                                                   u16* __restrict__ wos)
{
    int bid = blockIdx.x, tid = threadIdx.x;
    if (bid < NT) {
        int i = bid, j = tid;
        int acc = 0;
        #pragma unroll 8
        for (int s = 0; s < SD; ++s)
            acc += mask[s * NT + i] * mask[s * NT + j];
        rdenom[i * NT + j] = 1.0f / (float)max(acc, 1);
    } else {
        int idx = (bid - NT) * 384 + tid;     // 0..16383
        if (idx < 16384) {
            int c = idx >> 9, g = (idx >> 6) & 7, lane = idx & 63;
            const float* src = wo + (g * 16 + (lane & 15)) * 1024 + c * 32 + (lane >> 4) * 8;
            u16x8 pk;
            #pragma unroll
            for (int j = 0; j < 8; ++j) pk[j] = f2bf(src[j]);
            *(u16x8*)(wos + ((c * 8 + g) * 64 + lane) * 8) = pk;
        }
    }
}

// ---------------- Kernel 3: fused OPM + down-projection ----------------
// Block = 4 waves, tile 16 i x 8 j x 128 o, 32 c-chunks. All per-chunk global
// loads are single contiguous 1 KB segments (pre-swizzled layouts).
// Single-buffered wof/af (reload right after consumption, distance >= 1 chunk).
// __launch_bounds__(256,3): target 3 blocks/CU (12 waves) on the unified RF.
__global__ __launch_bounds__(256, 3) void opm_kernel(
    const u16* __restrict__ aws,  // [32][24][2][512]  fragment order
    const u16* __restrict__ bt,   // [384][32][64]     b[j][d][s]
    const u16* __restrict__ wos,  // [32][8][64][8]    fragment order
    const float* __restrict__ rdenom,
    const float* __restrict__ bo,
    float* __restrict__ out)      // [384][384][128]
{
    __shared__ u16 zbuf[2][128 * 32];   // 2 x 8 KB

    int bid = blockIdx.x;
    int ig = bid / 48;
    int jb = bid % 48;
    int tid = threadIdx.x;
    int w = tid >> 6, lane = tid & 63;
    int l15 = lane & 15, quad = lane >> 4;
    int mh = w & 1, nh = w >> 1;
    int swz = (l15 >> 1) & 3;

    // persistent bt fragments: wave w owns stage-A mtiles w*4..w*4+3
    short8 btf[4][2];
    #pragma unroll
    for (int mt4 = 0; mt4 < 4; ++mt4) {
        int mt = w * 4 + mt4;
        int j = mt >> 1, dh = mt & 1;
        const u16* p = bt + ((jb * 8 + j) * CH + dh * 16 + l15) * SD + quad * 8;
        btf[mt4][0] = *(const short8*)(p);
        btf[mt4][1] = *(const short8*)(p + 32);
    }

    const u16* abase = aws + ig * 1024 + lane * 8;         // + c*24576 + h*512
    const u16* wbase = wos + (nh * 4) * 512 + lane * 8;    // + c*4096 + ni*512

    f32x4 acc[4][4];
    #pragma unroll
    for (int mi = 0; mi < 4; ++mi)
        #pragma unroll
        for (int ni = 0; ni < 4; ++ni)
            acc[mi][ni] = (f32x4){0.f, 0.f, 0.f, 0.f};

    auto loadAf = [&](int c, short8* dst) {
        dst[0] = *(const short8*)(abase + c * 24576);
        dst[1] = *(const short8*)(abase + c * 24576 + 512);
    };
    auto loadWof = [&](int c, short8* dst) {
        #pragma unroll
        for (int ni = 0; ni < 4; ++ni)
            dst[ni] = *(const short8*)(wbase + c * 4096 + ni * 512);
    };
    auto stageA = [&](const short8* a, u16* buf) {
        #pragma unroll
        for (int mt4 = 0; mt4 < 4; ++mt4) {
            f32x4 za = {0.f, 0.f, 0.f, 0.f};
            za = MFMA16(btf[mt4][0], a[0], za);
            za = MFMA16(btf[mt4][1], a[1], za);
            int mt = w * 4 + mt4;
            int j = mt >> 1;
            int row = j * 16 + l15;
            int chunk = ((mt & 1) * 2 + (quad >> 1)) ^ swz;
            u16x4 pk;
            #pragma unroll
            for (int r = 0; r < 4; ++r) pk[r] = f2bf(za[r]);
            *(u16x4*)((char*)buf + row * 64 + chunk * 16 + (quad & 1) * 8) = pk;
        }
    };
    auto stageB = [&](const u16* buf, const short8* wof) {
        short8 zf[4];
        int chunk = quad ^ swz;
        #pragma unroll
        for (int mi = 0; mi < 4; ++mi) {
            int row = (mh * 4 + mi) * 16 + l15;
            zf[mi] = *(const short8*)((const char*)buf + row * 64 + chunk * 16);
        }
        #pragma unroll
        for (int mi = 0; mi < 4; ++mi)
            #pragma unroll
            for (int ni = 0; ni < 4; ++ni)
                acc[mi][ni] = MFMA16(zf[mi], wof[ni], acc[mi][ni]);
    };

    // ---- pipeline prologue ----
    short8 af[2], wof[4];
    loadAf(0, af);
    loadWof(0, wof);
    stageA(af, zbuf[0]);      // chunk 0
    loadAf(1, af);            // af(1)
    LDS_BARRIER();

    // ---- main loop: 1 chunk/iter, single-buffered frags, 1 LDS barrier ----
    for (int t = 0; t < 32; ++t) {
        stageB(zbuf[t & 1], wof);                       // consume chunk t
        if (t < 31) stageA(af, zbuf[(t + 1) & 1]);      // produce chunk t+1
        loadWof(t + 1 < 32 ? t + 1 : 31, wof);          // wof(t+1)
        loadAf(t + 2 < 32 ? t + 2 : 31, af);            // af(t+2)
        LDS_BARRIER();
    }

    // ---- epilogue: rdenom, bias, store ----
    float bov[4];
    #pragma unroll
    for (int ni = 0; ni < 4; ++ni) bov[ni] = bo[nh * 64 + ni * 16 + l15];
    #pragma unroll
    for (int mi = 0; mi < 4; ++mi) {
        int j_g = jb * 8 + mh * 4 + mi;
        #pragma unroll
        for (int r = 0; r < 4; ++r) {
            int i_g = ig * 16 + quad * 4 + r;
            float rd = rdenom[i_g * NT + j_g];
            float* orow = out + (i_g * NT + j_g) * CO + nh * 64 + l15;
            #pragma unroll
            for (int ni = 0; ni < 4; ++ni)
                orow[ni * 16] = acc[mi][ni][r] * rd + bov[ni];
        }
    }
}

// ---------------- launch ----------------
extern "C" void kernel_launch(void* const* d_in, const int* in_sizes, int n_in,
                              void* d_out, int out_size, void* d_ws, size_t ws_size,
                              hipStream_t stream) {
    const float* m     = (const float*)d_in[0];
    const int*   mask  = (const int*)d_in[1];
    const float* gamma = (const float*)d_in[2];
    const float* beta  = (const float*)d_in[3];
    const float* Wa    = (const float*)d_in[4];
    const float* Wb    = (const float*)d_in[5];
    const float* Wo    = (const float*)d_in[6];
    const float* bo    = (const float*)d_in[7];
    float* out = (float*)d_out;

    char* ws = (char*)d_ws;
    u16*   aws   = (u16*)(ws);                    // 1.5 MB fragment-order a
    u16*   btp   = (u16*)(ws + 1572864);          // 1.5 MB b[j][d][s]
    u16*   wos   = (u16*)(ws + 3145728);          // 256 KB fragment-order wo
    float* rden  = (float*)(ws + 3407872);        // 576 KB

    ln_proj_kernel<<<NT * 4, 128, 0, stream>>>(m, mask, gamma, beta, Wa, Wb, aws, btp);
    prep_kernel<<<NT + 43, 384, 0, stream>>>(mask, rden, Wo, wos);
    opm_kernel<<<24 * 48, 256, 0, stream>>>(aws, btp, wos, rden, bo, out);
}

// Round 7
// 188.158 us; speedup vs baseline: 1.2380x; 1.0186x over previous
//
#include <hip/hip_runtime.h>
#include <hip/hip_bf16.h>

typedef __attribute__((ext_vector_type(8))) short short8;
typedef __attribute__((ext_vector_type(4))) float f32x4;
typedef unsigned short u16;
typedef __attribute__((ext_vector_type(4))) u16 u16x4;
typedef __attribute__((ext_vector_type(8))) u16 u16x8;

#define LN_EPS 1e-5f
#define NT 384
#define SD 64
#define CH 32
#define CO 128

#define MFMA16(a, b, c) __builtin_amdgcn_mfma_f32_16x16x32_bf16(a, b, c, 0, 0, 0)
// LDS-only barrier: drains lgkm but NOT vmcnt -> global prefetches stay in flight.
#define LDS_BARRIER() asm volatile("s_waitcnt lgkmcnt(0)\n\ts_barrier" ::: "memory")

static __device__ __forceinline__ u16 f2bf(float v) {
    __hip_bfloat16 h = __float2bfloat16(v);
    return *reinterpret_cast<u16*>(&h);
}

// ---------------- Kernel 1: LayerNorm + dual projection + mask ----------------
// Grid 96 = 24 ig x 2 h x 2 sq. Block owns 16 n x 16 s. Projection results are
// transposed through LDS (pst) and written as full-line coalesced stores in
// MFMA fragment order for BOTH a (aws) and b (bts).
__global__ __launch_bounds__(256) void ln_proj_kernel(
    const float* __restrict__ m, const int* __restrict__ mask,
    const float* __restrict__ gamma, const float* __restrict__ beta,
    const float* __restrict__ Wa, const float* __restrict__ Wb,
    u16* __restrict__ aws, u16* __restrict__ bts)
{
    __shared__ float Wl[2][64][33];    // [side][k][c], bank=(k+c)%32 conflict-free
    __shared__ float mn_s[64][260];    // [k][n*16+sl], k-stride 260 -> 8-way max
    __shared__ u16   pst[64 * 264];    // [(side*32+c)][n*16+oct*8+j], stride 264
    __shared__ float mf_s[16][16];     // [sl][n]

    int bid = blockIdx.x;
    int ig = bid >> 2, h = (bid >> 1) & 1, sq = bid & 1;
    int s_base = h * 32 + sq * 16;
    int tid = threadIdx.x;
    int wv = tid >> 6, lane = tid & 63;

    // stage W (transposed into LDS)
    #pragma unroll
    for (int rep = 0; rep < 2; ++rep) {
        int p = rep * 1024 + tid * 4;
        int c = p >> 6, k0 = p & 63;
        float4 va = *(const float4*)(Wa + p);
        float4 vb = *(const float4*)(Wb + p);
        Wl[0][k0 + 0][c] = va.x; Wl[0][k0 + 1][c] = va.y;
        Wl[0][k0 + 2][c] = va.z; Wl[0][k0 + 3][c] = va.w;
        Wl[1][k0 + 0][c] = vb.x; Wl[1][k0 + 1][c] = vb.y;
        Wl[1][k0 + 2][c] = vb.z; Wl[1][k0 + 3][c] = vb.w;
    }
    { // mask tile
        int sl = tid >> 4, n = tid & 15;
        mf_s[sl][n] = (float)mask[(s_base + sl) * NT + ig * 16 + n];
    }

    // LayerNorm: 256 rows, 4 waves x 64 rows, lane = c_in
    float gl = gamma[lane], bl = beta[lane];
    #pragma unroll 2
    for (int it = 0; it < 64; ++it) {
        int r = wv * 64 + it;
        int n = r & 15, sl = r >> 4;
        float x = m[((s_base + sl) * NT + ig * 16 + n) * 64 + lane];
        float v = x;
        #pragma unroll
        for (int off = 1; off < 64; off <<= 1) v += __shfl_xor(v, off);
        float mu = v * (1.0f / 64.0f);
        float d = x - mu;
        float v2 = d * d;
        #pragma unroll
        for (int off = 1; off < 64; off <<= 1) v2 += __shfl_xor(v2, off);
        float rstd = rsqrtf(v2 * (1.0f / 64.0f) + LN_EPS);
        mn_s[lane][n * 16 + sl] = d * rstd * gl + bl;
    }
    __syncthreads();

    // projection: lane = (c, side); wave handles 8 (n, oct) row-units
    {
        int c = tid & 31, side = (tid >> 5) & 1;
        #pragma unroll 2
        for (int uu = 0; uu < 8; ++uu) {
            int u = wv * 8 + uu;
            int n = u >> 1, oct = u & 1;
            float acc[8];
            #pragma unroll
            for (int j = 0; j < 8; ++j) acc[j] = 0.f;
            for (int k = 0; k < 64; ++k) {
                float wk = Wl[side][k][c];
                f32x4 m0 = *(const f32x4*)&mn_s[k][n * 16 + oct * 8];
                f32x4 m1 = *(const f32x4*)&mn_s[k][n * 16 + oct * 8 + 4];
                #pragma unroll
                for (int j = 0; j < 4; ++j) {
                    acc[j]     += m0[j] * wk;
                    acc[4 + j] += m1[j] * wk;
                }
            }
            u16x8 pk;
            #pragma unroll
            for (int j = 0; j < 8; ++j) pk[j] = f2bf(acc[j] * mf_s[oct * 8 + j][n]);
            *(u16x8*)&pst[(side * 32 + c) * 264 + n * 16 + oct * 8] = pk;
        }
    }
    __syncthreads();

    // write-out: 64 regions (32 a-c + 32 b-(n,dh)) x 4 subs, full-line coalesced
    {
        int region = tid >> 2, sub = tid & 3;
        if (region < 32) {
            int cc = region;
            const u16* src = &pst[cc * 264];
            u16* dst = aws + ((cc * 24 + ig) * 2 + h) * 512 + sq * 256;
            #pragma unroll
            for (int r8 = 0; r8 < 8; ++r8) {
                int o = r8 * 32 + sub * 8;
                int q01 = o >> 7, nn = (o >> 3) & 15;
                *(u16x8*)(dst + o) = *(const u16x8*)(src + nn * 16 + q01 * 8);
            }
        } else {
            int rr = region - 32;
            int n = rr >> 1, dh = rr & 1;
            u16* dst = bts + ((ig * 16 + n) * 2 + h) * 1024 + dh * 512 + sq * 256;
            #pragma unroll
            for (int r8 = 0; r8 < 8; ++r8) {
                int o = r8 * 32 + sub * 8;
                int q01 = o >> 7, l15 = (o >> 3) & 15;
                *(u16x8*)(dst + o) =
                    *(const u16x8*)(&pst[(32 + dh * 16 + l15) * 264 + n * 16 + q01 * 8]);
            }
        }
    }
}

// ---------------- Kernel 2: denom + Wo -> per-chunk fragment order ----------------
__global__ __launch_bounds__(384) void prep_kernel(const int* __restrict__ mask,
                                                   float* __restrict__ rdenom,
                                                   const float* __restrict__ wo,
                                                   u16* __restrict__ wos)
{
    int bid = blockIdx.x, tid = threadIdx.x;
    if (bid < NT) {
        int i = bid, j = tid;
        int acc = 0;
        #pragma unroll 8
        for (int s = 0; s < SD; ++s)
            acc += mask[s * NT + i] * mask[s * NT + j];
        rdenom[i * NT + j] = 1.0f / (float)max(acc, 1);
    } else {
        int idx = (bid - NT) * 384 + tid;     // 0..16383
        if (idx < 16384) {
            int c = idx >> 9, g = (idx >> 6) & 7, lane = idx & 63;
            const float* src = wo + (g * 16 + (lane & 15)) * 1024 + c * 32 + (lane >> 4) * 8;
            u16x8 pk;
            #pragma unroll
            for (int j = 0; j < 8; ++j) pk[j] = f2bf(src[j]);
            *(u16x8*)(wos + ((c * 8 + g) * 64 + lane) * 8) = pk;
        }
    }
}

// ---------------- Kernel 3: fused OPM + down-projection ----------------
// 2 c-chunks per barrier, 4 z-buffers (32 KB). 48 MFMA/wave between barriers.
__global__ __launch_bounds__(256, 2) void opm_kernel(
    const u16* __restrict__ aws,  // [32][24][2][512]   fragment order
    const u16* __restrict__ bts,  // [384][2][2][512]   fragment order
    const u16* __restrict__ wos,  // [32][8][64][8]     fragment order
    const float* __restrict__ rdenom,
    const float* __restrict__ bo,
    float* __restrict__ out)      // [384][384][128]
{
    __shared__ u16 zbuf[4][128 * 32];   // 4 x 8 KB

    int bid = blockIdx.x;
    int ig = bid / 48;
    int jb = bid % 48;
    int tid = threadIdx.x;
    int w = tid >> 6, lane = tid & 63;
    int l15 = lane & 15, quad = lane >> 4;
    int mh = w & 1, nh = w >> 1;
    int swz = (l15 >> 1) & 3;

    // persistent bt fragments (contiguous 1 KB loads from bts)
    short8 btf[4][2];
    #pragma unroll
    for (int mt4 = 0; mt4 < 4; ++mt4) {
        int mt = w * 4 + mt4;
        #pragma unroll
        for (int ks = 0; ks < 2; ++ks)
            btf[mt4][ks] = *(const short8*)(bts +
                ((jb * 8 + (mt >> 1)) * 2 + ks) * 1024 + (mt & 1) * 512 + lane * 8);
    }

    const u16* abase = aws + ig * 1024 + lane * 8;         // + c*24576 + h*512
    const u16* wbase = wos + (nh * 4) * 512 + lane * 8;    // + c*4096 + ni*512

    f32x4 acc[4][4];
    #pragma unroll
    for (int mi = 0; mi < 4; ++mi)
        #pragma unroll
        for (int ni = 0; ni < 4; ++ni)
            acc[mi][ni] = (f32x4){0.f, 0.f, 0.f, 0.f};

    auto loadAf = [&](int c, short8* dst) {
        dst[0] = *(const short8*)(abase + c * 24576);
        dst[1] = *(const short8*)(abase + c * 24576 + 512);
    };
    auto loadWof = [&](int c, short8* dst) {
        #pragma unroll
        for (int ni = 0; ni < 4; ++ni)
            dst[ni] = *(const short8*)(wbase + c * 4096 + ni * 512);
    };
    auto stageA = [&](const short8* a, u16* buf) {
        #pragma unroll
        for (int mt4 = 0; mt4 < 4; ++mt4) {
            f32x4 za = {0.f, 0.f, 0.f, 0.f};
            za = MFMA16(btf[mt4][0], a[0], za);
            za = MFMA16(btf[mt4][1], a[1], za);
            int mt = w * 4 + mt4;
            int row = (mt >> 1) * 16 + l15;
            int chunk = ((mt & 1) * 2 + (quad >> 1)) ^ swz;
            u16x4 pk;
            #pragma unroll
            for (int r = 0; r < 4; ++r) pk[r] = f2bf(za[r]);
            *(u16x4*)((char*)buf + row * 64 + chunk * 16 + (quad & 1) * 8) = pk;
        }
    };
    auto stageB = [&](const u16* buf, const short8* wof) {
        short8 zf[4];
        int chunk = quad ^ swz;
        #pragma unroll
        for (int mi = 0; mi < 4; ++mi) {
            int row = (mh * 4 + mi) * 16 + l15;
            zf[mi] = *(const short8*)((const char*)buf + row * 64 + chunk * 16);
        }
        #pragma unroll
        for (int mi = 0; mi < 4; ++mi)
            #pragma unroll
            for (int ni = 0; ni < 4; ++ni)
                acc[mi][ni] = MFMA16(zf[mi], wof[ni], acc[mi][ni]);
    };

    // ---- prologue ----
    short8 afA[2], afB[2], wofA[4], wofB[4];
    loadAf(0, afA); loadWof(0, wofA);
    loadAf(1, afB); loadWof(1, wofB);
    stageA(afA, zbuf[0]); loadAf(2, afA);
    stageA(afB, zbuf[1]); loadAf(3, afB);
    LDS_BARRIER();

    // ---- main loop: 2 chunks per barrier ----
    for (int t = 0; t < 32; t += 2) {
        if (t + 2 < 32) stageA(afA, zbuf[(t + 2) & 3]);
        loadAf(t + 4 < 32 ? t + 4 : 31, afA);
        if (t + 3 < 32) stageA(afB, zbuf[(t + 3) & 3]);
        loadAf(t + 5 < 32 ? t + 5 : 31, afB);
        stageB(zbuf[t & 3], wofA);
        loadWof(t + 2 < 32 ? t + 2 : 31, wofA);
        stageB(zbuf[(t + 1) & 3], wofB);
        loadWof(t + 3 < 32 ? t + 3 : 31, wofB);
        LDS_BARRIER();
    }

    // ---- epilogue: rdenom, bias, store ----
    float bov[4];
    #pragma unroll
    for (int ni = 0; ni < 4; ++ni) bov[ni] = bo[nh * 64 + ni * 16 + l15];
    #pragma unroll
    for (int mi = 0; mi < 4; ++mi) {
        int j_g = jb * 8 + mh * 4 + mi;
        #pragma unroll
        for (int r = 0; r < 4; ++r) {
            int i_g = ig * 16 + quad * 4 + r;
            float rd = rdenom[i_g * NT + j_g];
            float* orow = out + (i_g * NT + j_g) * CO + nh * 64 + l15;
            #pragma unroll
            for (int ni = 0; ni < 4; ++ni)
                orow[ni * 16] = acc[mi][ni][r] * rd + bov[ni];
        }
    }
}

// ---------------- launch ----------------
extern "C" void kernel_launch(void* const* d_in, const int* in_sizes, int n_in,
                              void* d_out, int out_size, void* d_ws, size_t ws_size,
                              hipStream_t stream) {
    const float* m     = (const float*)d_in[0];
    const int*   mask  = (const int*)d_in[1];
    const float* gamma = (const float*)d_in[2];
    const float* beta  = (const float*)d_in[3];
    const float* Wa    = (const float*)d_in[4];
    const float* Wb    = (const float*)d_in[5];
    const float* Wo    = (const float*)d_in[6];
    const float* bo    = (const float*)d_in[7];
    float* out = (float*)d_out;

    char* ws = (char*)d_ws;
    u16*   aws   = (u16*)(ws);                    // 1.5 MB fragment-order a
    u16*   bts   = (u16*)(ws + 1572864);          // 1.5 MB fragment-order b
    u16*   wos   = (u16*)(ws + 3145728);          // 256 KB fragment-order wo
    float* rden  = (float*)(ws + 3407872);        // 576 KB

    ln_proj_kernel<<<96, 256, 0, stream>>>(m, mask, gamma, beta, Wa, Wb, aws, bts);
    prep_kernel<<<NT + 43, 384, 0, stream>>>(mask, rden, Wo, wos);
    opm_kernel<<<24 * 48, 256, 0, stream>>>(aws, bts, wos, rden, bo, out);
}